// Round 2
// baseline (1849.154 us; speedup 1.0000x reference)
//
#include <hip/hip_runtime.h>

#define SPECIES_CAP 128
// d_ws float layout: [0..3]=a, [4..7]=c(normalized), [8]=p, [9]=d,
// [16..16+SPECIES_CAP)=z_f, [16+SPECIES_CAP .. 16+2*SPECIES_CAP)=z^p*d
#define WS_A   0
#define WS_C   4
#define WS_ZF  16
#define WS_ZPD (16 + SPECIES_CAP)

__global__ void zbl_setup(const float* __restrict__ a_raw,
                          const float* __restrict__ c_raw,
                          const float* __restrict__ p_raw,
                          const float* __restrict__ d_raw,
                          const int* __restrict__ index_to_z,
                          int n_species,
                          float* __restrict__ params)
{
    __shared__ float s_p, s_d;
    int t = threadIdx.x;
    if (t == 0) {
        float a[4], c[4];
        float csum = 0.0f;
        for (int i = 0; i < 4; ++i) {
            a[i] = log1pf(expf(a_raw[i]));          // softplus
            c[i] = log1pf(expf(c_raw[i]));
            csum += c[i];
        }
        for (int i = 0; i < 4; ++i) {
            params[WS_A + i] = a[i];
            params[WS_C + i] = c[i] / csum;
        }
        float p = log1pf(expf(p_raw[0]));
        float d = log1pf(expf(d_raw[0]));
        params[8] = p;
        params[9] = d;
        s_p = p;
        s_d = d;
    }
    __syncthreads();
    float p = s_p, d = s_d;
    for (int s = t; s < n_species && s < SPECIES_CAP; s += blockDim.x) {
        float z = (float)index_to_z[s];
        params[WS_ZF + s]  = z;
        params[WS_ZPD + s] = powf(z, p) * d;        // fold d into the table
    }
}

__device__ __forceinline__ void zbl_edge(
    float dist, float cut, int snd, int rcv,
    const int* __restrict__ node_species,
    const float* s_zf, const float* s_zpd,
    const float* s_a, const float* s_c,
    float* __restrict__ out)
{
    int si = node_species[rcv];
    int sj = node_species[snd];
    float zi = s_zf[si];
    float zj = s_zf[sj];
    float x = cut * zi * zj / (dist + 1e-8f);
    float rzd = dist * (s_zpd[si] + s_zpd[sj]);     // dist*(zi^p+zj^p)*d
    float y = s_c[0] * __expf(-s_a[0] * rzd)
            + s_c[1] * __expf(-s_a[1] * rzd)
            + s_c[2] * __expf(-s_a[2] * rzd)
            + s_c[3] * __expf(-s_a[3] * rzd);
    float sd = dist * (1.0f / 1.5f);
    float u1 = (sd > 1e-8f) ? sd : 1e-8f;
    float u2 = ((1.0f - sd) > 1e-8f) ? (1.0f - sd) : 1e-8f;
    float e_d  = __expf(-1.0f / u1);
    float e_1d = __expf(-1.0f / u2);
    float w = e_1d / (e_1d + e_d);
    // KE/2 folded into the final scale
    float energy = 7.199822675975274f * w * x * y;
    // Native HW fp32 atomic (global_atomic_add_f32), NOT the CAS loop that
    // plain atomicAdd(float*) lowers to without -munsafe-fp-atomics.
    unsafeAtomicAdd(out + rcv, energy);
}

__global__ __launch_bounds__(256) void zbl_edge_kernel(
    const float* __restrict__ distances,
    const float* __restrict__ cutoffs,
    const int* __restrict__ senders,
    const int* __restrict__ receivers,
    const int* __restrict__ node_species,
    const float* __restrict__ params,
    float* __restrict__ out,
    int E, int n_species)
{
    __shared__ float s_zf[SPECIES_CAP];
    __shared__ float s_zpd[SPECIES_CAP];
    __shared__ float s_a[4];
    __shared__ float s_c[4];
    int t = threadIdx.x;
    if (t < 4)              s_a[t]     = params[WS_A + t];
    else if (t < 8)         s_c[t - 4] = params[WS_C + (t - 4)];
    for (int s = t; s < SPECIES_CAP; s += blockDim.x) {
        s_zf[s]  = params[WS_ZF + s];
        s_zpd[s] = params[WS_ZPD + s];
    }
    __syncthreads();

    int base = (blockIdx.x * 256 + t) * 4;
    if (base + 4 <= E) {
        float4 d4 = *(const float4*)(distances + base);
        float4 c4 = *(const float4*)(cutoffs + base);
        int4   s4 = *(const int4*)(senders + base);
        int4   r4 = *(const int4*)(receivers + base);
        zbl_edge(d4.x, c4.x, s4.x, r4.x, node_species, s_zf, s_zpd, s_a, s_c, out);
        zbl_edge(d4.y, c4.y, s4.y, r4.y, node_species, s_zf, s_zpd, s_a, s_c, out);
        zbl_edge(d4.z, c4.z, s4.z, r4.z, node_species, s_zf, s_zpd, s_a, s_c, out);
        zbl_edge(d4.w, c4.w, s4.w, r4.w, node_species, s_zf, s_zpd, s_a, s_c, out);
    } else {
        for (int e = base; e < E; ++e) {
            zbl_edge(distances[e], cutoffs[e], senders[e], receivers[e],
                     node_species, s_zf, s_zpd, s_a, s_c, out);
        }
    }
}

extern "C" void kernel_launch(void* const* d_in, const int* in_sizes, int n_in,
                              void* d_out, int out_size, void* d_ws, size_t ws_size,
                              hipStream_t stream)
{
    const int*   node_species = (const int*)d_in[0];
    const float* distances    = (const float*)d_in[1];
    const float* cutoffs      = (const float*)d_in[2];
    const int*   senders      = (const int*)d_in[3];
    const int*   receivers    = (const int*)d_in[4];
    const int*   index_to_z   = (const int*)d_in[5];
    const float* a_raw        = (const float*)d_in[6];
    const float* c_raw        = (const float*)d_in[7];
    const float* p_raw        = (const float*)d_in[8];
    const float* d_raw        = (const float*)d_in[9];

    int E = in_sizes[1];
    int n_species = in_sizes[5];
    float* out    = (float*)d_out;
    float* params = (float*)d_ws;

    // Output must be zeroed every call (harness poisons it with 0xAA).
    hipMemsetAsync(d_out, 0, (size_t)out_size * sizeof(float), stream);

    zbl_setup<<<1, 128, 0, stream>>>(a_raw, c_raw, p_raw, d_raw,
                                     index_to_z, n_species, params);

    int nvec   = (E + 3) / 4;
    int blocks = (nvec + 255) / 256;
    zbl_edge_kernel<<<blocks, 256, 0, stream>>>(
        distances, cutoffs, senders, receivers, node_species,
        params, out, E, n_species);
}

// Round 3
// 1833.430 us; speedup vs baseline: 1.0086x; 1.0086x over previous
//
#include <hip/hip_runtime.h>

#define SPECIES_CAP 128
// params (float) layout in ws: [0..3]=a, [4..7]=c(norm), [8]=p, [9]=d,
// [16..144)=z_f, [144..272)=z^p*d
#define WS_A   0
#define WS_C   4
#define WS_ZF  16
#define WS_ZPD (16 + SPECIES_CAP)

// Binning geometry
#define NB       256          // node-range buckets
#define RSHIFT   12
#define RNODES   4096         // nodes per bucket = 1<<RSHIFT
#define NSUB     4            // sub-streams per bucket (counter decontention)
#define CNT_STRIDE 16         // uints per counter (64 B line padding)
#define SPLIT    8            // reduce blocks per bucket

// ws byte layout
#define PARAMS_OFF 0
#define CNT_OFF    4096
#define CNT_BYTES  ((size_t)NB * NSUB * CNT_STRIDE * 4)   // 64 KB
#define PAIRS_OFF  (CNT_OFF + CNT_BYTES)

__global__ void zbl_setup(const float* __restrict__ a_raw,
                          const float* __restrict__ c_raw,
                          const float* __restrict__ p_raw,
                          const float* __restrict__ d_raw,
                          const int* __restrict__ index_to_z,
                          int n_species,
                          float* __restrict__ params)
{
    __shared__ float s_p, s_d;
    int t = threadIdx.x;
    if (t == 0) {
        float a[4], c[4];
        float csum = 0.0f;
        for (int i = 0; i < 4; ++i) {
            a[i] = log1pf(expf(a_raw[i]));          // softplus
            c[i] = log1pf(expf(c_raw[i]));
            csum += c[i];
        }
        for (int i = 0; i < 4; ++i) {
            params[WS_A + i] = a[i];
            params[WS_C + i] = c[i] / csum;
        }
        float p = log1pf(expf(p_raw[0]));
        float d = log1pf(expf(d_raw[0]));
        params[8] = p;
        params[9] = d;
        s_p = p;
        s_d = d;
    }
    __syncthreads();
    float p = s_p, d = s_d;
    for (int s = t; s < n_species && s < SPECIES_CAP; s += blockDim.x) {
        float z = (float)index_to_z[s];
        params[WS_ZF + s]  = z;
        params[WS_ZPD + s] = powf(z, p) * d;        // fold d into the table
    }
}

__device__ __forceinline__ float zbl_energy(
    float dist, float cut, int snd, int rcv,
    const int* __restrict__ node_species,
    const float* s_zf, const float* s_zpd,
    const float* s_a, const float* s_c)
{
    int si = node_species[rcv];
    int sj = node_species[snd];
    float zi = s_zf[si];
    float zj = s_zf[sj];
    float x = cut * zi * zj / (dist + 1e-8f);
    float rzd = dist * (s_zpd[si] + s_zpd[sj]);     // dist*(zi^p+zj^p)*d
    float y = s_c[0] * __expf(-s_a[0] * rzd)
            + s_c[1] * __expf(-s_a[1] * rzd)
            + s_c[2] * __expf(-s_a[2] * rzd)
            + s_c[3] * __expf(-s_a[3] * rzd);
    float sd = dist * (1.0f / 1.5f);
    float u1 = (sd > 1e-8f) ? sd : 1e-8f;
    float u2 = ((1.0f - sd) > 1e-8f) ? (1.0f - sd) : 1e-8f;
    float e_d  = __expf(-1.0f / u1);
    float e_1d = __expf(-1.0f / u2);
    float w = e_1d / (e_1d + e_d);
    return 7.199822675975274f * w * x * y;          // KE/2 folded in
}

// ---- Pass 1: compute energy, append (rcv, energy) to node-range buckets ----
__global__ __launch_bounds__(256) void zbl_bin_kernel(
    const float* __restrict__ distances,
    const float* __restrict__ cutoffs,
    const int* __restrict__ senders,
    const int* __restrict__ receivers,
    const int* __restrict__ node_species,
    const float* __restrict__ params,
    unsigned* __restrict__ cnt,
    uint2* __restrict__ pairs,
    int cap,
    float* __restrict__ out,
    int E)
{
    __shared__ float s_zf[SPECIES_CAP];
    __shared__ float s_zpd[SPECIES_CAP];
    __shared__ float s_a[4];
    __shared__ float s_c[4];
    int t = threadIdx.x;
    if (t < 4)              s_a[t]     = params[WS_A + t];
    else if (t < 8)         s_c[t - 4] = params[WS_C + (t - 4)];
    for (int s = t; s < SPECIES_CAP; s += blockDim.x) {
        s_zf[s]  = params[WS_ZF + s];
        s_zpd[s] = params[WS_ZPD + s];
    }
    __syncthreads();

    int sub = t & (NSUB - 1);
    int base = (blockIdx.x * 256 + t) * 4;
    if (base + 4 <= E) {
        float4 d4 = *(const float4*)(distances + base);
        float4 c4 = *(const float4*)(cutoffs + base);
        int4   s4 = *(const int4*)(senders + base);
        int4   r4 = *(const int4*)(receivers + base);
        int   rc[4] = { r4.x, r4.y, r4.z, r4.w };
        int   sn[4] = { s4.x, s4.y, s4.z, s4.w };
        float dd[4] = { d4.x, d4.y, d4.z, d4.w };
        float cc[4] = { c4.x, c4.y, c4.z, c4.w };
        float en[4];
        unsigned bk[4], slot[4];
#pragma unroll
        for (int k = 0; k < 4; ++k)
            en[k] = zbl_energy(dd[k], cc[k], sn[k], rc[k],
                               node_species, s_zf, s_zpd, s_a, s_c);
#pragma unroll
        for (int k = 0; k < 4; ++k)
            bk[k] = (((unsigned)rc[k]) >> RSHIFT) * NSUB + sub;
#pragma unroll
        for (int k = 0; k < 4; ++k)
            slot[k] = atomicAdd(&cnt[bk[k] * CNT_STRIDE], 1u);
#pragma unroll
        for (int k = 0; k < 4; ++k) {
            if (slot[k] < (unsigned)cap)
                pairs[(size_t)bk[k] * cap + slot[k]] =
                    make_uint2((unsigned)rc[k], __float_as_uint(en[k]));
            else
                unsafeAtomicAdd(out + rc[k], en[k]);   // overflow fallback
        }
    } else {
        for (int e = base; e < E; ++e) {
            int rcv = receivers[e];
            float en = zbl_energy(distances[e], cutoffs[e], senders[e], rcv,
                                  node_species, s_zf, s_zpd, s_a, s_c);
            unsigned bk = (((unsigned)rcv) >> RSHIFT) * NSUB + sub;
            unsigned slot = atomicAdd(&cnt[bk * CNT_STRIDE], 1u);
            if (slot < (unsigned)cap)
                pairs[(size_t)bk * cap + slot] =
                    make_uint2((unsigned)rcv, __float_as_uint(en));
            else
                unsafeAtomicAdd(out + rcv, en);
        }
    }
}

// ---- Pass 2: per-bucket LDS reduction, coalesced-ish output ----
__global__ __launch_bounds__(256) void zbl_reduce_kernel(
    const unsigned* __restrict__ cnt,
    const uint2* __restrict__ pairs,
    int cap,
    float* __restrict__ out,
    int n_nodes)
{
    __shared__ float acc[RNODES];
    int b = blockIdx.x / SPLIT;
    int s = blockIdx.x % SPLIT;
    for (int i = threadIdx.x; i < RNODES; i += 256) acc[i] = 0.0f;
    __syncthreads();

    bool any = false;                       // block-uniform
    for (int sub = 0; sub < NSUB; ++sub) {
        int bs = b * NSUB + sub;
        int entries = min((int)cnt[bs * CNT_STRIDE], cap);
        int len = (entries + SPLIT - 1) / SPLIT;
        int i0 = s * len;
        int i1 = min(i0 + len, entries);
        if (i0 < i1) any = true;
        const uint2* pb = pairs + (size_t)bs * cap;
        for (int i = i0 + threadIdx.x; i < i1; i += 256) {
            uint2 pr = pb[i];
            atomicAdd(&acc[pr.x & (RNODES - 1)], __uint_as_float(pr.y));
        }
    }
    __syncthreads();
    if (!any) return;                       // uniform exit

    int nbase = b << RSHIFT;
    for (int i = threadIdx.x; i < RNODES; i += 256) {
        int idx = nbase + i;
        if (idx < n_nodes) {
            float v = acc[i];
            if (v != 0.0f) unsafeAtomicAdd(out + idx, v);
        }
    }
}

// ---- Fallback: direct scattered atomics (R1 behavior) ----
__global__ __launch_bounds__(256) void zbl_direct_kernel(
    const float* __restrict__ distances,
    const float* __restrict__ cutoffs,
    const int* __restrict__ senders,
    const int* __restrict__ receivers,
    const int* __restrict__ node_species,
    const float* __restrict__ params,
    float* __restrict__ out,
    int E)
{
    __shared__ float s_zf[SPECIES_CAP];
    __shared__ float s_zpd[SPECIES_CAP];
    __shared__ float s_a[4];
    __shared__ float s_c[4];
    int t = threadIdx.x;
    if (t < 4)              s_a[t]     = params[WS_A + t];
    else if (t < 8)         s_c[t - 4] = params[WS_C + (t - 4)];
    for (int s = t; s < SPECIES_CAP; s += blockDim.x) {
        s_zf[s]  = params[WS_ZF + s];
        s_zpd[s] = params[WS_ZPD + s];
    }
    __syncthreads();
    int base = (blockIdx.x * 256 + t) * 4;
    int lim = min(base + 4, E);
    for (int e = base; e < lim; ++e) {
        int rcv = receivers[e];
        float en = zbl_energy(distances[e], cutoffs[e], senders[e], rcv,
                              node_species, s_zf, s_zpd, s_a, s_c);
        unsafeAtomicAdd(out + rcv, en);
    }
}

extern "C" void kernel_launch(void* const* d_in, const int* in_sizes, int n_in,
                              void* d_out, int out_size, void* d_ws, size_t ws_size,
                              hipStream_t stream)
{
    const int*   node_species = (const int*)d_in[0];
    const float* distances    = (const float*)d_in[1];
    const float* cutoffs      = (const float*)d_in[2];
    const int*   senders      = (const int*)d_in[3];
    const int*   receivers    = (const int*)d_in[4];
    const int*   index_to_z   = (const int*)d_in[5];
    const float* a_raw        = (const float*)d_in[6];
    const float* c_raw        = (const float*)d_in[7];
    const float* p_raw        = (const float*)d_in[8];
    const float* d_raw        = (const float*)d_in[9];

    int E         = in_sizes[1];
    int n_species = in_sizes[5];
    int n_nodes   = in_sizes[0];
    float*    out    = (float*)d_out;
    float*    params = (float*)((char*)d_ws + PARAMS_OFF);
    unsigned* cnt    = (unsigned*)((char*)d_ws + CNT_OFF);
    uint2*    pairs  = (uint2*)((char*)d_ws + PAIRS_OFF);

    // Sub-stream capacity from available workspace. avg per sub-stream =
    // E/(NB*NSUB) = 31250 for E=32M; 40000 gives ~28% headroom (>>100 sigma
    // for uniform receivers); overflow edges take the direct-atomic path.
    size_t avail = (ws_size > PAIRS_OFF) ? (ws_size - PAIRS_OFF) : 0;
    long long cap_ll = (long long)(avail / ((size_t)NB * NSUB * sizeof(uint2)));
    int want = E / (NB * NSUB) + E / (NB * NSUB * 4) + 1024;  // ~1.28x avg
    int cap = (int)((cap_ll < (long long)want) ? cap_ll : (long long)want);

    hipMemsetAsync(d_out, 0, (size_t)out_size * sizeof(float), stream);
    zbl_setup<<<1, 128, 0, stream>>>(a_raw, c_raw, p_raw, d_raw,
                                     index_to_z, n_species, params);

    int nvec   = (E + 3) / 4;
    int blocks = (nvec + 255) / 256;

    if (cap >= 4096) {
        hipMemsetAsync(cnt, 0, CNT_BYTES, stream);
        zbl_bin_kernel<<<blocks, 256, 0, stream>>>(
            distances, cutoffs, senders, receivers, node_species,
            params, cnt, pairs, cap, out, E);
        zbl_reduce_kernel<<<NB * SPLIT, 256, 0, stream>>>(
            cnt, pairs, cap, out, n_nodes);
    } else {
        zbl_direct_kernel<<<blocks, 256, 0, stream>>>(
            distances, cutoffs, senders, receivers, node_species,
            params, out, E);
    }
}